// Round 6
// baseline (522.108 us; speedup 1.0000x reference)
//
#include <hip/hip_runtime.h>
#include <hip/hip_cooperative_groups.h>

namespace cg = cooperative_groups;

#define NN 10000
#define EE 160000
#define ETOT (EE + NN)
#define EMB 768
#define ODIM 1024
#define NEG 0.2f
#define CAP 56
#define TPB 256

// ================= mega-kernel workspace layout (4B units) =================
#define OFF_P      0          // 12288 : P precontract [k*16+j]
#define OFF_Q      12288      // 8
#define OFF_EAP    12296      // 256 : edge_attr per-wave partials
#define OFF_EAACC  12552      // 1 : edge_attr sum
#define OFF_CNTD   12556      // int[10000]
#define OFF_CNTS   22556      // int[10000]
#define OFF_A      32556      // 160000 : a_src(0..7), a_dst(8..15) per node
#define OFF_SRCD   192556     // int[10000*CAP]
#define OFF_DSTS   752556     // int[10000*CAP]
#define OFF_PACK   1312556    // int[170000] : pd | ps<<16
#define OFF_EXD    1482556    // 10000*CAP*8 : exp vals, dst-major
#define OFF_EXS    5962556    // 10000*CAP*8 : exp vals, src-major
#define OFF_RDEN   10442556   // 80000
#define OFF_Z      10522556   // 2*8*768
#define OFF_YPART  10534844   // 157*6144

__global__ __launch_bounds__(TPB, 2) void mega(
    const float* __restrict__ x, const int* __restrict__ ei,
    const float* __restrict__ edge_attr, const int* __restrict__ tptr,
    const int* __restrict__ iptr, const float* __restrict__ W,
    const float* __restrict__ att_src, const float* __restrict__ att_dst,
    const float* __restrict__ W_edge, const float* __restrict__ att_edge,
    const float* __restrict__ bias, const float* __restrict__ clf_W,
    const float* __restrict__ clf_b, float* __restrict__ ws,
    float* __restrict__ out) {
  __shared__ float smem[6144];   // 24 KB: >=2 blocks/CU under any LDS model
  cg::grid_group grid = cg::this_grid();
  const int t = threadIdx.x, bid = blockIdx.x;
  const int GS = gridDim.x;
  int* wsI = (int*)ws;

  // ======== P0: zero counters + P precontract + Q + edge_attr partials ========
  for (int i = bid * TPB + t; i < 20000; i += GS * TPB) wsI[OFF_CNTD + i] = 0;
  for (int u = bid; u < 113; u += GS) {
    if (u < 48) {
      int tid = u * TPB + t, k = tid >> 4, j = tid & 15, h = j & 7;
      const float* att = (j < 8) ? att_src : att_dst;
      const float* wp = W + k * ODIM + h * 128;
      const float* ap = att + h * 128;
      float acc = 0.f;
      #pragma unroll 8
      for (int c = 0; c < 128; ++c) acc += wp[c] * ap[c];
      ws[OFF_P + k * 16 + j] = acc;
    } else if (u == 48) {
      if (t < 8) {
        float acc = 0.f;
        #pragma unroll 8
        for (int c = 0; c < 128; ++c) acc += W_edge[t * 128 + c] * att_edge[t * 128 + c];
        ws[OFF_Q + t] = acc;
      }
    } else {
      int ue = u - 49;
      float acc = 0.f;
      for (int i = ue * TPB + t; i < EE; i += 64 * TPB) acc += edge_attr[i];
      #pragma unroll
      for (int o = 32; o > 0; o >>= 1) acc += __shfl_down(acc, o, 64);
      if ((t & 63) == 0) ws[OFF_EAP + ue * 4 + (t >> 6)] = acc;
    }
  }
  grid.sync();

  // ======== P1: A = x @ P (P in LDS, two 384-row halves) | fill | easum ========
  for (int u = bid; u < 980; u += GS) {
    if (u < 313) {
      int n = u * 32 + (t & 31);
      int jp = (t >> 5) * 2;
      float a0 = 0.f, a1 = 0.f;
      const float4* xr = (const float4*)(x + n * EMB);
      for (int half = 0; half < 2; ++half) {
        __syncthreads();
        for (int i = t; i < 1536; i += TPB)
          ((float4*)smem)[i] = ((const float4*)(ws + OFF_P + half * 6144))[i];
        __syncthreads();
        if (n < NN) {
          for (int kk = 0; kk < 96; ++kk) {
            float4 xv = xr[half * 96 + kk];
            int k4 = kk * 64 + jp;
            float2 p0 = *(const float2*)&smem[k4];
            float2 p1 = *(const float2*)&smem[k4 + 16];
            float2 p2 = *(const float2*)&smem[k4 + 32];
            float2 p3 = *(const float2*)&smem[k4 + 48];
            a0 += xv.x * p0.x + xv.y * p1.x + xv.z * p2.x + xv.w * p3.x;
            a1 += xv.x * p0.y + xv.y * p1.y + xv.z * p2.y + xv.w * p3.y;
          }
        }
      }
      if (n < NN) {
        ws[OFF_A + n * 16 + jp] = a0;
        ws[OFF_A + n * 16 + jp + 1] = a1;
      }
    } else if (u < 978) {
      int e = (u - 313) * TPB + t;
      if (e < ETOT) {
        int src, dst;
        if (e < EE) { src = ei[e]; dst = ei[EE + e]; } else { src = dst = e - EE; }
        int pd = atomicAdd(&wsI[OFF_CNTD + dst], 1);
        if (pd < CAP) wsI[OFF_SRCD + dst * CAP + pd] = src;
        int ps = atomicAdd(&wsI[OFF_CNTS + src], 1);
        if (ps < CAP) wsI[OFF_DSTS + src * CAP + ps] = dst;
        if (pd > CAP) pd = CAP;
        if (ps > CAP) ps = CAP;
        wsI[OFF_PACK + e] = pd | (ps << 16);
      }
    } else if (u == 978) {
      float a = 0.f;
      if (t < 64)
        a = ws[OFF_EAP + t] + ws[OFF_EAP + t + 64] + ws[OFF_EAP + t + 128]
          + ws[OFF_EAP + t + 192];
      #pragma unroll
      for (int o = 32; o > 0; o >>= 1) a += __shfl_down(a, o, 64);
      if (t == 0) ws[OFF_EAACC] = a;
    }
  }
  grid.sync();

  // ======== P2: edge-parallel exp -> EXD/EXS | bias-dot + out init ========
  for (int u = bid; u < 666; u += GS) {
    if (u < 665) {
      int e = u * TPB + t;
      if (e < ETOT) {
        int src, dst; float ea;
        if (e < EE) { src = ei[e]; dst = ei[EE + e]; ea = edge_attr[e]; }
        else { src = dst = e - EE; ea = ws[OFF_EAACC] * (1.0f / EE); }
        int pk = wsI[OFF_PACK + e];
        int pd = pk & 0xffff, ps = pk >> 16;
        const float4* as4 = (const float4*)(ws + OFF_A + src * 16);
        const float4* ad4 = (const float4*)(ws + OFF_A + dst * 16 + 8);
        float4 s0 = as4[0], s1 = as4[1], d0 = ad4[0], d1 = ad4[1];
        float asr[8] = {s0.x, s0.y, s0.z, s0.w, s1.x, s1.y, s1.z, s1.w};
        float ads[8] = {d0.x, d0.y, d0.z, d0.w, d1.x, d1.y, d1.z, d1.w};
        float ex[8];
        #pragma unroll
        for (int h = 0; h < 8; ++h) {
          float v = asr[h] + ads[h] + ea * ws[OFF_Q + h];
          v = (v >= 0.f) ? v : NEG * v;
          ex[h] = __expf(v);
        }
        float4 e0 = make_float4(ex[0], ex[1], ex[2], ex[3]);
        float4 e1 = make_float4(ex[4], ex[5], ex[6], ex[7]);
        if (pd < CAP) {
          float4* p = (float4*)(ws + OFF_EXD + (dst * CAP + pd) * 8);
          p[0] = e0; p[1] = e1;
        }
        if (ps < CAP) {
          float4* p = (float4*)(ws + OFF_EXS + (src * CAP + ps) * 8);
          p[0] = e0; p[1] = e1;
        }
      }
    } else {
      float b0 = 0.f, b1 = 0.f;
      for (int i = t; i < 3072; i += TPB) {
        float f = bias[i & 1023];
        b0 += f * clf_W[2 * i];
        b1 += f * clf_W[2 * i + 1];
      }
      #pragma unroll
      for (int o = 32; o > 0; o >>= 1) {
        b0 += __shfl_down(b0, o, 64);
        b1 += __shfl_down(b1, o, 64);
      }
      __syncthreads();
      if ((t & 63) == 0) { smem[t >> 6] = b0; smem[4 + (t >> 6)] = b1; }
      __syncthreads();
      if (t == 0) {
        out[0] = clf_b[0] + smem[0] + smem[1] + smem[2] + smem[3];
        out[1] = clf_b[1] + smem[4] + smem[5] + smem[6] + smem[7];
      }
    }
  }
  grid.sync();

  // ======== P3: reciprocal denominators per (dst,h) ========
  for (int u = bid; u < 313; u += GS) {
    int tg = u * TPB + t;
    if (tg < 80000) {
      int dst = tg >> 3, h = tg & 7;
      int deg = wsI[OFF_CNTD + dst]; if (deg > CAP) deg = CAP;
      const float* bp = ws + OFF_EXD + dst * (CAP * 8) + h;
      float den = 0.f;
      for (int j = 0; j < deg; ++j) den += bp[j * 8];
      ws[OFF_RDEN + tg] = 1.0f / den;
    }
  }
  grid.sync();

  // ======== P4: fused s-compute + y-partials | z for text/image ========
  for (int u = bid; u < 163; u += GS) {
    if (u < 157) {
      int base = u * 64;
      for (int w = t; w < 512; w += TPB) {
        int n = base + (w >> 3), h = w & 7;
        float s = 0.f;
        if (n < NN) {
          int deg = wsI[OFF_CNTS + n]; if (deg > CAP) deg = CAP;
          const float* er = ws + OFF_EXS + n * (CAP * 8) + h;
          const int* dr = wsI + OFF_DSTS + n * CAP;
          for (int j = 0; j < deg; ++j)
            s += er[j * 8] * ws[OFF_RDEN + dr[j] * 8 + h];
        }
        smem[w] = s;
      }
      __syncthreads();
      int nmax = NN - base; if (nmax > 64) nmax = 64;
      float acc[24];
      #pragma unroll
      for (int q = 0; q < 24; ++q) acc[q] = 0.f;
      for (int i = 0; i < nmax; ++i) {
        const float* xr = x + (base + i) * EMB;
        float x0 = xr[t], x1 = xr[t + 256], x2 = xr[t + 512];
        const float* sv = &smem[i * 8];
        #pragma unroll
        for (int h = 0; h < 8; ++h) {
          acc[h] += x0 * sv[h];
          acc[8 + h] += x1 * sv[h];
          acc[16 + h] += x2 * sv[h];
        }
      }
      float* yp = ws + OFF_YPART + u * 6144;
      #pragma unroll
      for (int h = 0; h < 8; ++h) {
        yp[h * 768 + t] = acc[h];
        yp[h * 768 + 256 + t] = acc[8 + h];
        yp[h * 768 + 512 + t] = acc[16 + h];
      }
      __syncthreads();
    } else {
      int r = u - 157, d = r / 3, ky = r % 3;
      int target = (d == 0) ? tptr[0] : iptr[0];
      float* wL = smem;
      int* srcS = (int*)(smem + 448);
      int* degP = (int*)(smem + 508);
      if (t == 0) { int dg = wsI[OFF_CNTD + target]; degP[0] = (dg > CAP) ? CAP : dg; }
      __syncthreads();
      int deg = degP[0];
      for (int idx = t; idx < deg * 8; idx += TPB) {
        int j = idx >> 3, h = idx & 7;
        wL[idx] = ws[OFF_EXD + (target * CAP + j) * 8 + h] * ws[OFF_RDEN + target * 8 + h];
        if (h == 0) srcS[j] = wsI[OFF_SRCD + target * CAP + j];
      }
      __syncthreads();
      int col = ky * 256 + t;
      float acc[8];
      #pragma unroll
      for (int h = 0; h < 8; ++h) acc[h] = 0.f;
      for (int j = 0; j < deg; ++j) {
        float xv = x[srcS[j] * EMB + col];
        const float* wv = &wL[j * 8];
        #pragma unroll
        for (int h = 0; h < 8; ++h) acc[h] += wv[h] * xv;
      }
      #pragma unroll
      for (int h = 0; h < 8; ++h) ws[OFF_Z + (d * 8 + h) * EMB + col] = acc[h];
      __syncthreads();
    }
  }
  grid.sync();

  // ======== P5: Y-reduce + projection + classifier dot -> atomicAdd out ========
  for (int u = bid; u < 64; u += GS) {
    int h = u >> 3, kc = u & 7, kbase = kc * 96;
    float* vY2 = smem;          // [192] split-b Y partials
    float* vL  = smem + 192;    // [288]: g[96], text[96], image[96]
    if (t < 192) {
      int k = t % 96, half = t / 96;
      float a = 0.f;
      for (int b = half; b < 157; b += 2)
        a += ws[OFF_YPART + b * 6144 + h * 768 + kbase + k];
      vY2[t] = a;
    } else {
      for (int i = t - 192; i < 192; i += 64) {
        int d = i / 96, k = i - d * 96;
        vL[96 + i] = ws[OFF_Z + (d * 8 + h) * EMB + kbase + k];
      }
    }
    __syncthreads();
    if (t < 96) vL[t] = (vY2[t] + vY2[t + 96]) * (1.0f / NN);
    __syncthreads();
    float l0 = 0.f, l1 = 0.f;
    if (t < 128) {
      int c = t;
      float a0 = 0.f, a1 = 0.f, a2 = 0.f;
      #pragma unroll 4
      for (int k = 0; k < 96; ++k) {
        float wv = W[(kbase + k) * ODIM + h * 128 + c];
        a0 += vL[k] * wv;
        a1 += vL[96 + k] * wv;
        a2 += vL[192 + k] * wv;
      }
      int ib = h * 128 + c;
      l0 = a0 * clf_W[2 * ib] + a1 * clf_W[2 * (1024 + ib)] + a2 * clf_W[2 * (2048 + ib)];
      l1 = a0 * clf_W[2 * ib + 1] + a1 * clf_W[2 * (1024 + ib) + 1] + a2 * clf_W[2 * (2048 + ib) + 1];
    }
    #pragma unroll
    for (int o = 32; o > 0; o >>= 1) {
      l0 += __shfl_down(l0, o, 64);
      l1 += __shfl_down(l1, o, 64);
    }
    __syncthreads();
    if ((t & 63) == 0) { smem[480 + (t >> 6)] = l0; smem[484 + (t >> 6)] = l1; }
    __syncthreads();
    if (t == 0) {
      atomicAdd(&out[0], smem[480] + smem[481] + smem[482] + smem[483]);
      atomicAdd(&out[1], smem[484] + smem[485] + smem[486] + smem[487]);
    }
    __syncthreads();
  }
}

// ===================== fallback: round-4 multi-kernel path =====================
#define FB_P      0
#define FB_Q      12288
#define FB_EAACC  12296
#define FB_CNTD   12304
#define FB_CNTS   22304
#define FB_ZSTART 12296
#define FB_ZCNT   20008
#define FB_A      32304
#define FB_APART  192304
#define FB_SRCD   1472304
#define FB_DSTS   2032304
#define FB_PACK   2592304
#define FB_EXD    2762304
#define FB_EXS    7242304
#define FB_RDEN   11722304
#define FB_S      11802304
#define FB_Z      11882304
#define FB_YPART  11894592
#define FB_FPART  12859200

__global__ __launch_bounds__(256) void f_k1f(
    const float* __restrict__ W, const float* __restrict__ att_src,
    const float* __restrict__ att_dst, const float* __restrict__ W_edge,
    const float* __restrict__ att_edge, const float* __restrict__ edge_attr,
    const int* __restrict__ ei, float* __restrict__ ws) {
  int b = blockIdx.x;
  if (b < 48) {
    int tid = b * 256 + threadIdx.x;
    int k = tid >> 4, j = tid & 15, h = j & 7;
    const float* att = (j < 8) ? att_src : att_dst;
    const float* wp = W + k * ODIM + h * 128;
    const float* ap = att + h * 128;
    float acc = 0.f;
    #pragma unroll 8
    for (int c = 0; c < 128; ++c) acc += wp[c] * ap[c];
    ws[FB_P + k * 16 + j] = acc;
  } else if (b == 48) {
    if (threadIdx.x < 8) {
      int h = threadIdx.x;
      float acc = 0.f;
      #pragma unroll 8
      for (int c = 0; c < 128; ++c) acc += W_edge[h * 128 + c] * att_edge[h * 128 + c];
      ws[FB_Q + h] = acc;
    }
  } else if (b < 113) {
    int bi = b - 49;
    float acc = 0.f;
    for (int i = bi * 256 + threadIdx.x; i < EE; i += 64 * 256) acc += edge_attr[i];
    #pragma unroll
    for (int off = 32; off > 0; off >>= 1) acc += __shfl_down(acc, off, 64);
    if ((threadIdx.x & 63) == 0) atomicAdd(&ws[FB_EAACC], acc);
  } else {
    int e = (b - 113) * 256 + threadIdx.x;
    if (e >= ETOT) return;
    int src, dst;
    if (e < EE) { src = ei[e]; dst = ei[EE + e]; } else { src = dst = e - EE; }
    int* cntd = (int*)(ws + FB_CNTD);
    int* cnts = (int*)(ws + FB_CNTS);
    int pd = atomicAdd(&cntd[dst], 1);
    if (pd < CAP) ((int*)(ws + FB_SRCD))[dst * CAP + pd] = src;
    int ps = atomicAdd(&cnts[src], 1);
    if (ps < CAP) ((int*)(ws + FB_DSTS))[src * CAP + ps] = dst;
    if (pd > CAP) pd = CAP;
    if (ps > CAP) ps = CAP;
    ((int*)(ws + FB_PACK))[e] = pd | (ps << 16);
  }
}

__global__ __launch_bounds__(256) void f_k3part(const float* __restrict__ x,
                                                float* __restrict__ ws) {
  __shared__ float pL[96 * 16];
  const int c = blockIdx.y;
  const int kbase = c * 96;
  for (int i = threadIdx.x; i < 96 * 16; i += 256) pL[i] = ws[FB_P + kbase * 16 + i];
  __syncthreads();
  int n = blockIdx.x * 256 + threadIdx.x;
  if (n >= NN) return;
  float acc[16];
  #pragma unroll
  for (int j = 0; j < 16; ++j) acc[j] = 0.f;
  const float4* xr = (const float4*)(x + n * EMB + kbase);
  for (int kk = 0; kk < 24; ++kk) {
    float4 xv = xr[kk];
    const float* pr = &pL[kk * 64];
    #pragma unroll
    for (int j = 0; j < 16; ++j) acc[j] += xv.x * pr[j];
    #pragma unroll
    for (int j = 0; j < 16; ++j) acc[j] += xv.y * pr[16 + j];
    #pragma unroll
    for (int j = 0; j < 16; ++j) acc[j] += xv.z * pr[32 + j];
    #pragma unroll
    for (int j = 0; j < 16; ++j) acc[j] += xv.w * pr[48 + j];
  }
  float4* ap = (float4*)(ws + FB_APART + c * 160000 + n * 16);
  ap[0] = make_float4(acc[0], acc[1], acc[2], acc[3]);
  ap[1] = make_float4(acc[4], acc[5], acc[6], acc[7]);
  ap[2] = make_float4(acc[8], acc[9], acc[10], acc[11]);
  ap[3] = make_float4(acc[12], acc[13], acc[14], acc[15]);
}

__global__ __launch_bounds__(256) void f_reduceA(float* __restrict__ ws) {
  int i = blockIdx.x * 256 + threadIdx.x;
  if (i >= 40000) return;
  float4 r = make_float4(0.f, 0.f, 0.f, 0.f);
  #pragma unroll
  for (int c = 0; c < 8; ++c) {
    float4 a = ((const float4*)(ws + FB_APART + c * 160000))[i];
    r.x += a.x; r.y += a.y; r.z += a.z; r.w += a.w;
  }
  ((float4*)(ws + FB_A))[i] = r;
}

__global__ __launch_bounds__(256) void f_kE(const int* __restrict__ ei,
                                            const float* __restrict__ edge_attr,
                                            float* __restrict__ ws) {
  int e = blockIdx.x * 256 + threadIdx.x;
  if (e >= ETOT) return;
  int src, dst; float ea;
  if (e < EE) { src = ei[e]; dst = ei[EE + e]; ea = edge_attr[e]; }
  else { src = dst = e - EE; ea = ws[FB_EAACC] * (1.0f / EE); }
  int pk = ((const int*)(ws + FB_PACK))[e];
  int pd = pk & 0xffff, ps = pk >> 16;
  const float4* as4 = (const float4*)(ws + FB_A + src * 16);
  const float4* ad4 = (const float4*)(ws + FB_A + dst * 16 + 8);
  float4 s0 = as4[0], s1 = as4[1], d0 = ad4[0], d1 = ad4[1];
  float asr[8] = {s0.x, s0.y, s0.z, s0.w, s1.x, s1.y, s1.z, s1.w};
  float ads[8] = {d0.x, d0.y, d0.z, d0.w, d1.x, d1.y, d1.z, d1.w};
  float ex[8];
  #pragma unroll
  for (int h = 0; h < 8; ++h) {
    float v = asr[h] + ads[h] + ea * ws[FB_Q + h];
    v = (v >= 0.f) ? v : NEG * v;
    ex[h] = __expf(v);
  }
  float4 e0 = make_float4(ex[0], ex[1], ex[2], ex[3]);
  float4 e1 = make_float4(ex[4], ex[5], ex[6], ex[7]);
  if (pd < CAP) {
    float4* p = (float4*)(ws + FB_EXD + (dst * CAP + pd) * 8);
    p[0] = e0; p[1] = e1;
  }
  if (ps < CAP) {
    float4* p = (float4*)(ws + FB_EXS + (src * CAP + ps) * 8);
    p[0] = e0; p[1] = e1;
  }
}

__global__ __launch_bounds__(256) void f_kD(float* __restrict__ ws) {
  int t = blockIdx.x * 256 + threadIdx.x;
  if (t >= NN * 8) return;
  int dst = t >> 3, h = t & 7;
  int deg = ((const int*)(ws + FB_CNTD))[dst];
  if (deg > CAP) deg = CAP;
  const float* base = ws + FB_EXD + dst * (CAP * 8) + h;
  float den = 0.f;
  for (int j = 0; j < deg; ++j) den += base[j * 8];
  ws[FB_RDEN + dst * 8 + h] = 1.0f / den;
}

__global__ __launch_bounds__(256) void f_kSZ(const float* __restrict__ x,
                                             const int* __restrict__ tptr,
                                             const int* __restrict__ iptr,
                                             float* __restrict__ ws) {
  if (blockIdx.x < 313) {
    int t = blockIdx.x * 256 + threadIdx.x;
    if (t >= NN * 8) return;
    int src = t >> 3, h = t & 7;
    int deg = ((const int*)(ws + FB_CNTS))[src];
    if (deg > CAP) deg = CAP;
    const int* dstrow = (const int*)(ws + FB_DSTS) + src * CAP;
    const float* exrow = ws + FB_EXS + src * (CAP * 8) + h;
    float s = 0.f;
    for (int j = 0; j < deg; ++j)
      s += exrow[j * 8] * ws[FB_RDEN + dstrow[j] * 8 + h];
    ws[FB_S + src * 8 + h] = s;
  } else {
    __shared__ float wL[CAP * 8];
    __shared__ int srcS[CAP];
    __shared__ int degS;
    int r = blockIdx.x - 313;
    int d = r / 3, ky = r % 3;
    int target = (d == 0) ? tptr[0] : iptr[0];
    if (threadIdx.x == 0) {
      int dg = ((const int*)(ws + FB_CNTD))[target];
      degS = (dg > CAP) ? CAP : dg;
    }
    __syncthreads();
    int deg = degS;
    for (int idx = threadIdx.x; idx < deg * 8; idx += 256) {
      int j = idx >> 3, h = idx & 7;
      wL[idx] = ws[FB_EXD + (target * CAP + j) * 8 + h] * ws[FB_RDEN + target * 8 + h];
      if (h == 0) srcS[j] = ((const int*)(ws + FB_SRCD))[target * CAP + j];
    }
    __syncthreads();
    int col = ky * 256 + threadIdx.x;
    float acc[8];
    #pragma unroll
    for (int h = 0; h < 8; ++h) acc[h] = 0.f;
    for (int j = 0; j < deg; ++j) {
      float xv = x[srcS[j] * EMB + col];
      const float* wv = &wL[j * 8];
      #pragma unroll
      for (int h = 0; h < 8; ++h) acc[h] += wv[h] * xv;
    }
    #pragma unroll
    for (int h = 0; h < 8; ++h) ws[FB_Z + (d * 8 + h) * EMB + col] = acc[h];
  }
}

__global__ __launch_bounds__(256) void f_k7s(const float* __restrict__ x,
                                             float* __restrict__ ws) {
  __shared__ float sL[64 * 8];
  int base = blockIdx.x * 64;
  int c = blockIdx.y;
  for (int i = threadIdx.x; i < 512; i += 256) {
    int n = base + (i >> 3);
    sL[i] = (n < NN) ? ws[FB_S + base * 8 + i] : 0.f;
  }
  __syncthreads();
  int col = c * 256 + threadIdx.x;
  float acc[8];
  #pragma unroll
  for (int h = 0; h < 8; ++h) acc[h] = 0.f;
  int nmax = (NN - base < 64) ? (NN - base) : 64;
  for (int i = 0; i < nmax; ++i) {
    float xv = x[(base + i) * EMB + col];
    const float* sv = &sL[i * 8];
    #pragma unroll
    for (int h = 0; h < 8; ++h) acc[h] += xv * sv[h];
  }
  float* yp = ws + FB_YPART + (blockIdx.x * 3 + c) * 2048;
  #pragma unroll
  for (int h = 0; h < 8; ++h) yp[h * 256 + threadIdx.x] = acc[h];
}

__global__ __launch_bounds__(128) void f_k8part(const float* __restrict__ W,
                                                float* __restrict__ ws) {
  __shared__ float vL[3 * 96];
  int h = blockIdx.x, kc = blockIdx.y;
  int kbase = kc * 96;
  for (int k = threadIdx.x; k < 96; k += 128) {
    int col = kbase + k, cc = col >> 8, ck = col & 255;
    float acc = 0.f;
    for (int b = 0; b < 157; ++b)
      acc += ws[FB_YPART + (b * 3 + cc) * 2048 + h * 256 + ck];
    vL[k] = acc * (1.0f / NN);
  }
  for (int i = threadIdx.x; i < 192; i += 128) {
    int d = i / 96, k = i - d * 96;
    vL[96 + i] = ws[FB_Z + (d * 8 + h) * EMB + kbase + k];
  }
  __syncthreads();
  int c = threadIdx.x;
  float a0 = 0.f, a1 = 0.f, a2 = 0.f;
  #pragma unroll 4
  for (int k = 0; k < 96; ++k) {
    float wv = W[(kbase + k) * ODIM + h * 128 + c];
    a0 += vL[k] * wv;
    a1 += vL[96 + k] * wv;
    a2 += vL[192 + k] * wv;
  }
  float* fp = ws + FB_FPART + kc * 3072 + h * 128 + c;
  fp[0] = a0; fp[1024] = a1; fp[2048] = a2;
}

__global__ __launch_bounds__(256) void f_k9(const float* __restrict__ clf_W,
                                            const float* __restrict__ clf_b,
                                            const float* __restrict__ bias,
                                            const float* __restrict__ ws,
                                            float* __restrict__ out) {
  float a0 = 0.f, a1 = 0.f;
  for (int i = threadIdx.x; i < 3072; i += 256) {
    float f = bias[i & 1023];
    #pragma unroll
    for (int kc = 0; kc < 8; ++kc) f += ws[FB_FPART + kc * 3072 + i];
    a0 += f * clf_W[i * 2 + 0];
    a1 += f * clf_W[i * 2 + 1];
  }
  #pragma unroll
  for (int off = 32; off > 0; off >>= 1) {
    a0 += __shfl_down(a0, off, 64);
    a1 += __shfl_down(a1, off, 64);
  }
  __shared__ float r0[4], r1[4];
  int wid = threadIdx.x >> 6, lane = threadIdx.x & 63;
  if (lane == 0) { r0[wid] = a0; r1[wid] = a1; }
  __syncthreads();
  if (threadIdx.x == 0) {
    out[0] = r0[0] + r0[1] + r0[2] + r0[3] + clf_b[0];
    out[1] = r1[0] + r1[1] + r1[2] + r1[3] + clf_b[1];
  }
}

extern "C" void kernel_launch(void* const* d_in, const int* in_sizes, int n_in,
                              void* d_out, int out_size, void* d_ws, size_t ws_size,
                              hipStream_t stream) {
  const float* x        = (const float*)d_in[0];
  const int*   ei       = (const int*)d_in[1];
  const float* edge_attr= (const float*)d_in[2];
  const int*   tptr     = (const int*)d_in[3];
  const int*   iptr     = (const int*)d_in[4];
  const float* W        = (const float*)d_in[5];
  const float* att_src  = (const float*)d_in[6];
  const float* att_dst  = (const float*)d_in[7];
  const float* W_edge   = (const float*)d_in[8];
  const float* att_edge = (const float*)d_in[9];
  const float* bias     = (const float*)d_in[10];
  const float* clf_W    = (const float*)d_in[11];
  const float* clf_b    = (const float*)d_in[12];
  float* ws  = (float*)d_ws;
  float* out = (float*)d_out;

  // Decide cooperative path from pure device queries (capture-safe, deterministic)
  int dev = 0, coop = 0, cus = 0, maxb = 0;
  hipGetDevice(&dev);
  hipDeviceGetAttribute(&coop, hipDeviceAttributeCooperativeLaunch, dev);
  hipDeviceGetAttribute(&cus, hipDeviceAttributeMultiprocessorCount, dev);
  hipOccupancyMaxActiveBlocksPerMultiprocessor(&maxb, mega, TPB, 0);
  long maxgrid = (long)maxb * (long)cus;
  int grid = (maxgrid > 512) ? 512 : (int)maxgrid;

  bool launched = false;
  if (coop && grid >= 8) {
    void* kargs[] = {
      (void*)&x, (void*)&ei, (void*)&edge_attr, (void*)&tptr, (void*)&iptr,
      (void*)&W, (void*)&att_src, (void*)&att_dst, (void*)&W_edge,
      (void*)&att_edge, (void*)&bias, (void*)&clf_W, (void*)&clf_b,
      (void*)&ws, (void*)&out
    };
    hipError_t err = hipLaunchCooperativeKernel((void*)mega, dim3(grid), dim3(TPB),
                                                kargs, 0, stream);
    launched = (err == hipSuccess);
  }

  if (!launched) {
    // fallback: proven multi-kernel pipeline (round 4)
    hipMemsetAsync(ws + FB_ZSTART, 0, FB_ZCNT * sizeof(float), stream);
    f_k1f<<<778, 256, 0, stream>>>(W, att_src, att_dst, W_edge, att_edge,
                                   edge_attr, ei, ws);
    dim3 g3(40, 8);
    f_k3part<<<g3, 256, 0, stream>>>(x, ws);
    f_reduceA<<<157, 256, 0, stream>>>(ws);
    f_kE<<<665, 256, 0, stream>>>(ei, edge_attr, ws);
    f_kD<<<313, 256, 0, stream>>>(ws);
    f_kSZ<<<319, 256, 0, stream>>>(x, tptr, iptr, ws);
    dim3 g7(157, 3);
    f_k7s<<<g7, 256, 0, stream>>>(x, ws);
    dim3 g8(8, 8);
    f_k8part<<<g8, 128, 0, stream>>>(W, ws);
    f_k9<<<1, 256, 0, stream>>>(clf_W, clf_b, bias, ws, out);
  }
}

// Round 7
// 192.721 us; speedup vs baseline: 2.7091x; 2.7091x over previous
//
#include <hip/hip_runtime.h>

#define NN 10000
#define EE 160000
#define ETOT (EE + NN)
#define EMB 768
#define ODIM 1024
#define NEG 0.2f
#define CAP 56          // max in/out degree ~45 (Binom(160k,1e-4) max + self-loop)

// ---- workspace layout (4B units) ----
#define OFF_P      0          // 12288 : P precontract [k*16+j] (src j<8, dst j>=8)
#define OFF_Q      12288      // 8
#define OFF_EAACC  12296      // 1 (zeroed)
#define OFF_CNTD   12304      // int[10000] (zeroed)
#define OFF_CNTS   22304      // int[10000] (zeroed)
#define ZERO_START 12296
#define ZERO_CNT   20008
#define OFF_A      32304      // 10000*16 : a_src(0..7), a_dst(8..15)
#define OFF_SRCD   192304     // int[10000*CAP] : src per dst-bucket slot
#define OFF_DSTS   752304     // int[10000*CAP] : dst per src-bucket slot
#define OFF_PACK   1312304    // int[170000] : pd | ps<<16
#define OFF_EXD    1482304    // 10000*CAP*8 : exp vals, dst-major
#define OFF_EXS    5962304    // 10000*CAP*8 : exp vals, src-major
#define OFF_RDEN   10442304   // 80000 : 1/denominator per (dst,h)
#define OFF_S      10522304   // 80000 : outgoing attention sums
#define OFF_Z      10602304   // 2*8*768
#define OFF_YPART  10614592   // 157*6144 : y partials [b][h*768+col]
// end 11579200 floats = 46.3 MB

// K1F: P/Q precontract + edge_attr sum + bucket fill (block roles)
__global__ __launch_bounds__(256) void k1f(
    const float* __restrict__ W, const float* __restrict__ att_src,
    const float* __restrict__ att_dst, const float* __restrict__ W_edge,
    const float* __restrict__ att_edge, const float* __restrict__ edge_attr,
    const int* __restrict__ ei, float* __restrict__ ws) {
  int b = blockIdx.x;
  if (b < 48) {
    int tid = b * 256 + threadIdx.x;   // 0..12287
    int k = tid >> 4, j = tid & 15, h = j & 7;
    const float* att = (j < 8) ? att_src : att_dst;
    const float* wp = W + k * ODIM + h * 128;
    const float* ap = att + h * 128;
    float acc = 0.f;
    #pragma unroll 8
    for (int c = 0; c < 128; ++c) acc += wp[c] * ap[c];
    ws[OFF_P + k * 16 + j] = acc;
  } else if (b == 48) {
    if (threadIdx.x < 8) {
      int h = threadIdx.x;
      float acc = 0.f;
      #pragma unroll 8
      for (int c = 0; c < 128; ++c) acc += W_edge[h * 128 + c] * att_edge[h * 128 + c];
      ws[OFF_Q + h] = acc;
    }
  } else if (b < 113) {
    int bi = b - 49;   // 64 blocks: sum edge_attr
    float acc = 0.f;
    for (int i = bi * 256 + threadIdx.x; i < EE; i += 64 * 256) acc += edge_attr[i];
    #pragma unroll
    for (int off = 32; off > 0; off >>= 1) acc += __shfl_down(acc, off, 64);
    if ((threadIdx.x & 63) == 0) atomicAdd(&ws[OFF_EAACC], acc);
  } else {
    int e = (b - 113) * 256 + threadIdx.x;
    if (e >= ETOT) return;
    int src, dst;
    if (e < EE) { src = ei[e]; dst = ei[EE + e]; } else { src = dst = e - EE; }
    int* cntd = (int*)(ws + OFF_CNTD);
    int* cnts = (int*)(ws + OFF_CNTS);
    int pd = atomicAdd(&cntd[dst], 1);
    if (pd < CAP) ((int*)(ws + OFF_SRCD))[dst * CAP + pd] = src;
    int ps = atomicAdd(&cnts[src], 1);
    if (ps < CAP) ((int*)(ws + OFF_DSTS))[src * CAP + ps] = dst;
    if (pd > CAP) pd = CAP;
    if (ps > CAP) ps = CAP;
    ((int*)(ws + OFF_PACK))[e] = pd | (ps << 16);
  }
}

// KAX: A = x @ P, full P in 48KB LDS (3 blocks/CU), in-LDS reduction
__global__ __launch_bounds__(256) void kAx(const float* __restrict__ x,
                                           float* __restrict__ ws) {
  __shared__ float smem[12288];
  for (int i = threadIdx.x; i < 3072; i += 256)
    ((float4*)smem)[i] = ((const float4*)(ws + OFF_P))[i];
  __syncthreads();
  int nl = threadIdx.x & 31, cg = threadIdx.x >> 5;   // cg in [0,8): 96-col group
  int n = blockIdx.x * 32 + nl;
  float a[16];
  #pragma unroll
  for (int j = 0; j < 16; ++j) a[j] = 0.f;
  if (n < NN) {
    const float4* xr = (const float4*)(x + n * EMB + cg * 96);
    for (int kk = 0; kk < 24; ++kk) {
      float4 xv = xr[kk];
      const float* pr = &smem[(cg * 96 + kk * 4) * 16];
      #pragma unroll
      for (int j = 0; j < 16; ++j) a[j] += xv.x * pr[j];
      #pragma unroll
      for (int j = 0; j < 16; ++j) a[j] += xv.y * pr[16 + j];
      #pragma unroll
      for (int j = 0; j < 16; ++j) a[j] += xv.z * pr[32 + j];
      #pragma unroll
      for (int j = 0; j < 16; ++j) a[j] += xv.w * pr[48 + j];
    }
  }
  __syncthreads();   // all P reads done; reuse smem for partials
  #pragma unroll
  for (int j = 0; j < 16; ++j) smem[(cg * 16 + j) * 33 + nl] = a[j];
  __syncthreads();
  for (int w = threadIdx.x; w < 512; w += 256) {
    int rnl = w >> 4, j = w & 15;
    int nn = blockIdx.x * 32 + rnl;
    if (nn < NN) {
      float s = 0.f;
      #pragma unroll
      for (int c2 = 0; c2 < 8; ++c2) s += smem[(c2 * 16 + j) * 33 + rnl];
      ws[OFF_A + nn * 16 + j] = s;
    }
  }
}

// KE: edge-parallel exp -> EXD/EXS; last block: bias-dot init of out
__global__ __launch_bounds__(128) void kE(const int* __restrict__ ei,
                                          const float* __restrict__ edge_attr,
                                          const float* __restrict__ bias,
                                          const float* __restrict__ clf_W,
                                          const float* __restrict__ clf_b,
                                          float* __restrict__ out,
                                          float* __restrict__ ws) {
  __shared__ float red[4];
  int* wsI = (int*)ws;
  if (blockIdx.x < 1329) {
    int e = blockIdx.x * 128 + threadIdx.x;
    if (e >= ETOT) return;
    int src, dst; float ea;
    if (e < EE) { src = ei[e]; dst = ei[EE + e]; ea = edge_attr[e]; }
    else { src = dst = e - EE; ea = ws[OFF_EAACC] * (1.0f / EE); }
    int pk = wsI[OFF_PACK + e];
    int pd = pk & 0xffff, ps = pk >> 16;
    const float4* as4 = (const float4*)(ws + OFF_A + src * 16);
    const float4* ad4 = (const float4*)(ws + OFF_A + dst * 16 + 8);
    float4 s0 = as4[0], s1 = as4[1], d0 = ad4[0], d1 = ad4[1];
    float asr[8] = {s0.x, s0.y, s0.z, s0.w, s1.x, s1.y, s1.z, s1.w};
    float ads[8] = {d0.x, d0.y, d0.z, d0.w, d1.x, d1.y, d1.z, d1.w};
    float ex[8];
    #pragma unroll
    for (int h = 0; h < 8; ++h) {
      float v = asr[h] + ads[h] + ea * ws[OFF_Q + h];
      v = (v >= 0.f) ? v : NEG * v;
      ex[h] = __expf(v);
    }
    float4 e0 = make_float4(ex[0], ex[1], ex[2], ex[3]);
    float4 e1 = make_float4(ex[4], ex[5], ex[6], ex[7]);
    if (pd < CAP) {
      float4* p = (float4*)(ws + OFF_EXD + (dst * CAP + pd) * 8);
      p[0] = e0; p[1] = e1;
    }
    if (ps < CAP) {
      float4* p = (float4*)(ws + OFF_EXS + (src * CAP + ps) * 8);
      p[0] = e0; p[1] = e1;
    }
  } else {
    // bias contribution: out = clf_b + sum_i bias[i&1023]*clf_W[i]
    int t = threadIdx.x;
    float b0 = 0.f, b1 = 0.f;
    for (int i = t; i < 3072; i += 128) {
      float f = bias[i & 1023];
      b0 += f * clf_W[2 * i];
      b1 += f * clf_W[2 * i + 1];
    }
    #pragma unroll
    for (int o = 32; o > 0; o >>= 1) {
      b0 += __shfl_down(b0, o, 64);
      b1 += __shfl_down(b1, o, 64);
    }
    if ((t & 63) == 0) { red[(t >> 6) * 2] = b0; red[(t >> 6) * 2 + 1] = b1; }
    __syncthreads();
    if (t == 0) {
      out[0] = clf_b[0] + red[0] + red[2];
      out[1] = clf_b[1] + red[1] + red[3];
    }
  }
}

// KD: rden per (dst,h) from contiguous EXD rows
__global__ __launch_bounds__(128) void kD(float* __restrict__ ws) {
  int t = blockIdx.x * 128 + threadIdx.x;   // 0..79999
  int dst = t >> 3, h = t & 7;
  int deg = ((const int*)(ws + OFF_CNTD))[dst];
  if (deg > CAP) deg = CAP;
  const float* base = ws + OFF_EXD + dst * (CAP * 8) + h;
  float den = 0.f;
  for (int j = 0; j < deg; ++j) den += base[j * 8];
  ws[OFF_RDEN + t] = 1.0f / den;
}

// KSZ: blocks 0..624: s per (src,h); blocks 625..636: z for text/image
__global__ __launch_bounds__(128) void kSZ(const float* __restrict__ x,
                                           const int* __restrict__ tptr,
                                           const int* __restrict__ iptr,
                                           float* __restrict__ ws) {
  __shared__ float sm[512];
  if (blockIdx.x < 625) {
    int t = blockIdx.x * 128 + threadIdx.x;  // 0..79999
    int src = t >> 3, h = t & 7;
    int deg = ((const int*)(ws + OFF_CNTS))[src];
    if (deg > CAP) deg = CAP;
    const int* dstrow = (const int*)(ws + OFF_DSTS) + src * CAP;
    const float* exrow = ws + OFF_EXS + src * (CAP * 8) + h;
    float s = 0.f;
    for (int j = 0; j < deg; ++j)
      s += exrow[j * 8] * ws[OFF_RDEN + dstrow[j] * 8 + h];
    ws[OFF_S + t] = s;
  } else {
    float* wL = sm;                 // [448]
    int* srcS = (int*)(sm + 448);   // [56]
    int* degP = (int*)(sm + 508);
    int r = blockIdx.x - 625;       // 0..11
    int d = r / 6, kc = r % 6;      // d: 0=text 1=image; kc: 128-col chunk
    int target = (d == 0) ? tptr[0] : iptr[0];
    if (threadIdx.x == 0) {
      int dg = ((const int*)(ws + OFF_CNTD))[target];
      degP[0] = (dg > CAP) ? CAP : dg;
    }
    __syncthreads();
    int deg = degP[0];
    for (int idx = threadIdx.x; idx < deg * 8; idx += 128) {
      int j = idx >> 3, h = idx & 7;
      wL[idx] = ws[OFF_EXD + (target * CAP + j) * 8 + h]
              * ws[OFF_RDEN + target * 8 + h];
      if (h == 0) srcS[j] = ((const int*)(ws + OFF_SRCD))[target * CAP + j];
    }
    __syncthreads();
    int col = kc * 128 + threadIdx.x;
    float acc[8];
    #pragma unroll
    for (int h = 0; h < 8; ++h) acc[h] = 0.f;
    for (int j = 0; j < deg; ++j) {
      float xv = x[srcS[j] * EMB + col];
      const float* wv = &wL[j * 8];
      #pragma unroll
      for (int h = 0; h < 8; ++h) acc[h] += wv[h] * xv;
    }
    #pragma unroll
    for (int h = 0; h < 8; ++h) ws[OFF_Z + (d * 8 + h) * EMB + col] = acc[h];
  }
}

// K7S: y-partials: YPART[bx][h*768 + col] = sum over 64 nodes of s[n][h]*x[n][col]
__global__ __launch_bounds__(256) void k7s(const float* __restrict__ x,
                                           float* __restrict__ ws) {
  __shared__ float sL[64 * 8];
  int base = blockIdx.x * 64;
  int c = blockIdx.y;
  for (int i = threadIdx.x; i < 512; i += 256) {
    int n = base + (i >> 3);
    sL[i] = (n < NN) ? ws[OFF_S + base * 8 + i] : 0.f;
  }
  __syncthreads();
  int col = c * 256 + threadIdx.x;
  float acc[8];
  #pragma unroll
  for (int h = 0; h < 8; ++h) acc[h] = 0.f;
  int nmax = (NN - base < 64) ? (NN - base) : 64;
  for (int i = 0; i < nmax; ++i) {
    float xv = x[(base + i) * EMB + col];
    const float* sv = &sL[i * 8];
    #pragma unroll
    for (int h = 0; h < 8; ++h) acc[h] += xv * sv[h];
  }
  float* yp = ws + OFF_YPART + blockIdx.x * 6144 + col;
  #pragma unroll
  for (int h = 0; h < 8; ++h) yp[h * 768] = acc[h];
}

// K8: Y-reduce + projection + classifier dot -> atomicAdd into out
__global__ __launch_bounds__(128) void k8(const float* __restrict__ W,
                                          const float* __restrict__ clf_W,
                                          float* __restrict__ out,
                                          float* __restrict__ ws) {
  __shared__ float vL[144];
  __shared__ float red[4];
  int h = blockIdx.x, kc = blockIdx.y, kbase = kc * 48;
  for (int i = threadIdx.x; i < 144; i += 128) {
    int d = i / 48, k = i - d * 48;
    float v;
    if (d == 0) {
      float acc = 0.f;
      for (int b = 0; b < 157; ++b)
        acc += ws[OFF_YPART + b * 6144 + h * 768 + kbase + k];
      v = acc * (1.0f / NN);
    } else {
      v = ws[OFF_Z + ((d - 1) * 8 + h) * 768 + kbase + k];
    }
    vL[i] = v;
  }
  __syncthreads();
  int c = threadIdx.x;
  float a0 = 0.f, a1 = 0.f, a2 = 0.f;
  #pragma unroll 4
  for (int k = 0; k < 48; ++k) {
    float wv = W[(kbase + k) * ODIM + h * 128 + c];
    a0 += vL[k] * wv;
    a1 += vL[48 + k] * wv;
    a2 += vL[96 + k] * wv;
  }
  int ib = h * 128 + c;
  float l0 = a0 * clf_W[2 * ib] + a1 * clf_W[2 * (1024 + ib)]
           + a2 * clf_W[2 * (2048 + ib)];
  float l1 = a0 * clf_W[2 * ib + 1] + a1 * clf_W[2 * (1024 + ib) + 1]
           + a2 * clf_W[2 * (2048 + ib) + 1];
  #pragma unroll
  for (int o = 32; o > 0; o >>= 1) {
    l0 += __shfl_down(l0, o, 64);
    l1 += __shfl_down(l1, o, 64);
  }
  if ((threadIdx.x & 63) == 0) {
    red[(threadIdx.x >> 6) * 2] = l0;
    red[(threadIdx.x >> 6) * 2 + 1] = l1;
  }
  __syncthreads();
  if (threadIdx.x == 0) {
    atomicAdd(&out[0], red[0] + red[2]);
    atomicAdd(&out[1], red[1] + red[3]);
  }
}

extern "C" void kernel_launch(void* const* d_in, const int* in_sizes, int n_in,
                              void* d_out, int out_size, void* d_ws, size_t ws_size,
                              hipStream_t stream) {
  const float* x        = (const float*)d_in[0];
  const int*   ei       = (const int*)d_in[1];
  const float* edge_attr= (const float*)d_in[2];
  const int*   tptr     = (const int*)d_in[3];
  const int*   iptr     = (const int*)d_in[4];
  const float* W        = (const float*)d_in[5];
  const float* att_src  = (const float*)d_in[6];
  const float* att_dst  = (const float*)d_in[7];
  const float* W_edge   = (const float*)d_in[8];
  const float* att_edge = (const float*)d_in[9];
  const float* bias     = (const float*)d_in[10];
  const float* clf_W    = (const float*)d_in[11];
  const float* clf_b    = (const float*)d_in[12];
  float* ws  = (float*)d_ws;
  float* out = (float*)d_out;

  hipMemsetAsync(ws + ZERO_START, 0, ZERO_CNT * sizeof(float), stream);
  k1f<<<778, 256, 0, stream>>>(W, att_src, att_dst, W_edge, att_edge, edge_attr, ei, ws);
  kAx<<<313, 256, 0, stream>>>(x, ws);
  kE<<<1330, 128, 0, stream>>>(ei, edge_attr, bias, clf_W, clf_b, out, ws);
  kD<<<625, 128, 0, stream>>>(ws);
  kSZ<<<637, 128, 0, stream>>>(x, tptr, iptr, ws);
  dim3 g7(157, 3);
  k7s<<<g7, 256, 0, stream>>>(x, ws);
  dim3 g8(8, 16);
  k8<<<g8, 128, 0, stream>>>(W, clf_W, out, ws);
}